// Round 9
// baseline (281.075 us; speedup 1.0000x reference)
//
#include <hip/hip_runtime.h>
#include <math.h>

#define NTOK  16384
#define NW6   (NTOK * 6)
#define NSEG  4
#define SEGF4 128               // float4 per expert-row segment (512 dims)
#define D4    512               // float4 per full row
#define CHF4  16                // float4 per chunk (64 dims)
#define NCH   8                 // chunks per segment
#define TPB   128               // tokens per block
#define SCORES_FLOATS (NSEG * 18 * NTOK)   // 4.72 MB

#define DOT4(a, b) ((a).x*(b).x + (a).y*(b).y + (a).z*(b).z + (a).w*(b).w)

// DPP row_shl sum-tree: lane i adds lane i+N (out-of-range -> 0). After 4
// steps lane 0 of each 16-lane row holds the full row sum. (Verified R6/R8.)
template <int CTRL>
__device__ __forceinline__ float dpp_add(float v) {
    int moved = __builtin_amdgcn_update_dpp(0, __float_as_int(v),
                                            CTRL, 0xF, 0xF, true);
    return v + __int_as_float(moved);
}
__device__ __forceinline__ float row_reduce16(float v) {
    v = dpp_add<0x108>(v);   // row_shl:8
    v = dpp_add<0x104>(v);   // row_shl:4
    v = dpp_add<0x102>(v);   // row_shl:2
    v = dpp_add<0x101>(v);   // row_shl:1
    return v;
}

// ---------------- Phase 1: partial scores per D-segment ----------------
// Block: 4 waves x 32 tokens = 128 tokens, one 512-dim segment.
// Wave = 4 groups x 16 lanes; each group owns 8 tokens (acc[18][8]).
// x is streamed through a PER-WAVE private double-buffered LDS tile:
//   chunk loop: issue 8 global loads (chunk+1) -> 26 ds_reads + 576 FMA on
//   current chunk -> one vmcnt batch wait -> 8 ds_writes. No barriers in
//   the loop (each wave reads only its own staging); global latency is
//   covered by the full compute window instead of fragile register rotation.
__global__ __launch_bounds__(256, 1) void scores_kernel(
    const float* __restrict__ x,
    const float* __restrict__ We,
    const float* __restrict__ Wg,
    float* __restrict__ scores)
{
    __shared__ float4 wlds[18 * SEGF4];        // 36,864 B
    __shared__ float4 xs[4 * 2 * 32 * CHF4];   // 65,536 B (wave, buf, tok, f4)

    const int tid   = threadIdx.x;
    const int seg   = blockIdx.x & 3;
    const int strip = blockIdx.x >> 2;

    const float4* __restrict__ x4  = reinterpret_cast<const float4*>(x);
    const float4* __restrict__ We4 = reinterpret_cast<const float4*>(We);
    const float4* __restrict__ Wg4 = reinterpret_cast<const float4*>(Wg);

    // ---- stage the 18 x 512-dim W segment (coalesced, conflict-free) ----
#pragma unroll
    for (int k = 0; k < 9; ++k) {
        const int idx = k * 256 + tid;        // 0..2303 float4
        const int e = idx >> 7;               // 0..17
        const int d = idx & 127;
        const float4* src = (e < 16) ? (We4 + (size_t)e * D4)
                                     : (Wg4 + (size_t)(e - 16) * D4);
        wlds[idx] = src[seg * SEGF4 + d];
    }

    const int wave = tid >> 6;
    const int lane = tid & 63;
    const int grp  = lane >> 4;
    const int l16  = lane & 15;

    // This wave's tokens: strip*128 + wave*32 + grp*8 + t  (t = 0..7)
    const float4* __restrict__ xb =
        x4 + (size_t)(strip * TPB + wave * 32 + grp * 8) * D4 + seg * SEGF4;
    float4* __restrict__ xw = xs + wave * (2 * 32 * CHF4);   // wave-private

    // ---- prologue: stage chunk 0 into buf 0 ----
    {
        float4 v[8];
#pragma unroll
        for (int t = 0; t < 8; ++t) v[t] = xb[(size_t)t * D4 + l16];
#pragma unroll
        for (int t = 0; t < 8; ++t) xw[(grp * 8 + t) * CHF4 + l16] = v[t];
    }
    __syncthreads();   // W visible to all waves

    float acc[18][8];
#pragma unroll
    for (int e = 0; e < 18; ++e)
#pragma unroll
        for (int t = 0; t < 8; ++t) acc[e][t] = 0.f;

    for (int ch = 0; ch < NCH; ++ch) {
        const int cur = (ch & 1) * (32 * CHF4);
        const int nxt = ((ch + 1) & 1) * (32 * CHF4);

        // issue next chunk's 8 global loads first (in flight during compute)
        float4 nx[8];
        if (ch + 1 < NCH) {
#pragma unroll
            for (int t = 0; t < 8; ++t)
                nx[t] = xb[(size_t)t * D4 + (ch + 1) * CHF4 + l16];
        }

        // current chunk from LDS
        float4 xv[8];
#pragma unroll
        for (int t = 0; t < 8; ++t)
            xv[t] = xw[cur + (grp * 8 + t) * CHF4 + l16];

#pragma unroll
        for (int e = 0; e < 18; ++e) {
            const float4 w = wlds[e * SEGF4 + ch * CHF4 + l16];
#pragma unroll
            for (int t = 0; t < 8; ++t)
                acc[e][t] += DOT4(w, xv[t]);
        }

        // one vmcnt batch wait, then park next chunk in the other buffer
        if (ch + 1 < NCH) {
#pragma unroll
            for (int t = 0; t < 8; ++t)
                xw[nxt + (grp * 8 + t) * CHF4 + l16] = nx[t];
        }
    }

    // ---- reduce 144 sums across each 16-lane group (pure VALU) ----
#pragma unroll
    for (int e = 0; e < 18; ++e)
#pragma unroll
        for (int t = 0; t < 8; ++t)
            acc[e][t] = row_reduce16(acc[e][t]);

    if (l16 == 0) {
        const int tokbase = strip * TPB + wave * 32 + grp * 8;
#pragma unroll
        for (int e = 0; e < 18; ++e) {
            float* p = scores + (size_t)(seg * 18 + e) * NTOK + tokbase;
#pragma unroll
            for (int t = 0; t < 8; ++t) p[t] = acc[e][t];
        }
    }
}

// ---------------- Phase 2: combine segments + routing + aux ----------------
__global__ __launch_bounds__(256) void route_kernel(
    const float* __restrict__ scores,
    float* __restrict__ out,
    unsigned int* __restrict__ gcounts)
{
    __shared__ unsigned int lcnt[16];
    const int tid = threadIdx.x;
    if (tid < 16) lcnt[tid] = 0u;
    __syncthreads();

    const int tok = blockIdx.x * 256 + tid;

    float s[18];
#pragma unroll
    for (int e = 0; e < 18; ++e) {
        s[e] = scores[(size_t)(0 * 18 + e) * NTOK + tok]
             + scores[(size_t)(1 * 18 + e) * NTOK + tok]
             + scores[(size_t)(2 * 18 + e) * NTOK + tok]
             + scores[(size_t)(3 * 18 + e) * NTOK + tok];
    }

    const float g0 = 1.f / (1.f + expf(-s[16]));
    const float g1 = 1.f / (1.f + expf(-s[17]));

    // --- Group A: experts 0..7, top-1 of softmax ---
    int aidx = 0; float amax = s[0];
#pragma unroll
    for (int i = 1; i < 8; ++i)
        if (s[i] > amax) { amax = s[i]; aidx = i; }
    float asum = 0.f;
#pragma unroll
    for (int i = 0; i < 8; ++i) asum += expf(s[i] - amax);
    const float a_best = 1.f / asum;

    // --- Group B: experts 8..11, top-1, gated by g0 ---
    int bidx = 0; float bmax = s[8];
#pragma unroll
    for (int i = 1; i < 4; ++i)
        if (s[8 + i] > bmax) { bmax = s[8 + i]; bidx = i; }
    float bsum = 0.f;
#pragma unroll
    for (int i = 0; i < 4; ++i) bsum += expf(s[8 + i] - bmax);
    const float b_w = (g0 > 0.15f) ? ((1.f / bsum) * g0) : 0.f;

    // --- Group C: experts 12..15, top-2 of softmax, gated by g1 ---
    int c1 = 0; float cmax = s[12];
#pragma unroll
    for (int i = 1; i < 4; ++i)
        if (s[12 + i] > cmax) { cmax = s[12 + i]; c1 = i; }
    float csum = 0.f;
#pragma unroll
    for (int i = 0; i < 4; ++i) csum += expf(s[12 + i] - cmax);
    int c2 = -1; float c2v = -1e30f;
#pragma unroll
    for (int i = 0; i < 4; ++i)
        if (i != c1 && s[12 + i] > c2v) { c2v = s[12 + i]; c2 = i; }
    const float cg   = (g1 > 0.15f) ? g1 : 0.f;
    const float c_w1 = (1.f / csum) * cg;
    const float c_w2 = (expf(c2v - cmax) / csum) * cg;

    // --- normalize and write ---
    const float inv = 1.f / (a_best + b_w + c_w1 + c_w2 + 1e-8f);
    float2* ow = reinterpret_cast<float2*>(out + (size_t)tok * 6);
    ow[0] = make_float2(a_best * inv, b_w * inv);
    ow[1] = make_float2(c_w1 * inv, c_w2 * inv);
    ow[2] = make_float2(0.f, 0.f);
    float2* oi = reinterpret_cast<float2*>(out + NW6 + (size_t)tok * 6);
    oi[0] = make_float2((float)aidx, (float)(8 + bidx));
    oi[1] = make_float2((float)(12 + c1), (float)(12 + c2));
    oi[2] = make_float2(0.f, 0.f);

    atomicAdd(&lcnt[aidx], 1u);
    atomicAdd(&lcnt[8 + bidx], 1u);
    atomicAdd(&lcnt[12 + c1], 1u);
    atomicAdd(&lcnt[12 + c2], 1u);

    __syncthreads();
    if (tid < 16) {
        const unsigned int c = lcnt[tid];
        if (c) atomicAdd(&gcounts[tid], c);
    }
    __syncthreads();

    // Last-block ticket: aux loss. Reference bincount counts the 2 zero-pad
    // indices per token -> expert 0 gets +2*NTOK; total = 6*NTOK.
    if (tid == 0) {
        __threadfence();
        const unsigned int t = atomicAdd(&gcounts[16], 1u);
        if (t == gridDim.x - 1) {
            const float total = 6.0f * (float)NTOK;
            const float uni = 1.0f / 16.0f;
            float aux = 0.f;
            for (int e = 0; e < 16; ++e) {
                float c = (float)atomicAdd(&gcounts[e], 0u)
                          + (e == 0 ? 2.0f * (float)NTOK : 0.0f);
                aux += uni * (logf(uni) - logf(c / total));
            }
            out[2 * NW6] = aux * 0.01f;
        }
    }
}

extern "C" void kernel_launch(void* const* d_in, const int* in_sizes, int n_in,
                              void* d_out, int out_size, void* d_ws, size_t ws_size,
                              hipStream_t stream)
{
    const float* x  = (const float*)d_in[0];   // (4,4096,2048)
    const float* We = (const float*)d_in[1];   // (16,2048)
    const float* Wg = (const float*)d_in[2];   // (2,2048)
    float* out = (float*)d_out;

    float* scores = (float*)d_ws;                          // 4.72 MB
    unsigned int* counts = (unsigned int*)((char*)d_ws + SCORES_FLOATS * 4);

    hipMemsetAsync(counts, 0, 17 * sizeof(unsigned int), stream);

    // Phase 1: 128-token strips x 4 D-segments = 512 blocks.
    scores_kernel<<<dim3((NTOK / TPB) * NSEG), 256, 0, stream>>>(x, We, Wg, scores);
    // Phase 2 (stream-ordered after phase 1).
    route_kernel<<<dim3(NTOK / 256), 256, 0, stream>>>(scores, out, counts);
}

// Round 10
// 229.608 us; speedup vs baseline: 1.2242x; 1.2242x over previous
//
#include <hip/hip_runtime.h>
#include <math.h>

#define NTOK  16384
#define NW6   (NTOK * 6)
#define NSEG  4
#define SEGF4 128              // float4 per expert-row segment (512 dims)
#define D4    512              // float4 per full row
#define SCORES_FLOATS (NSEG * 18 * NTOK)   // 4.72 MB

#define DOT4(a, b) ((a).x*(b).x + (a).y*(b).y + (a).z*(b).z + (a).w*(b).w)

// DPP row_shl sum-tree: lane i adds lane i+N (out-of-range -> 0). After 4
// steps lane 0 of each 16-lane row holds the full row sum. (Verified R6/R8.)
template <int CTRL>
__device__ __forceinline__ float dpp_add(float v) {
    int moved = __builtin_amdgcn_update_dpp(0, __float_as_int(v),
                                            CTRL, 0xF, 0xF, true);
    return v + __int_as_float(moved);
}
__device__ __forceinline__ float row_reduce16(float v) {
    v = dpp_add<0x108>(v);   // row_shl:8
    v = dpp_add<0x104>(v);   // row_shl:4
    v = dpp_add<0x102>(v);   // row_shl:2
    v = dpp_add<0x101>(v);   // row_shl:1
    return v;
}

// ---------------- Phase 1: partial scores per D-segment ----------------
// R6 skeleton (wave = 4 groups x 16 lanes, group = 4 tokens, 36 KB W-segment
// in LDS, x float4 direct from global) with the expert dimension split into
// TWO PASSES of 9 experts. This cuts live accumulators 72 -> 36 so a 9-deep
// LDS batch + 4-deep global batch fit under the 128-VGPR/4-waves-per-SIMD
// occupancy point -- ILP and TLP simultaneously (R6 had TLP only, R8 ILP
// only). x is read twice from global (L1/L2/L3-hot on pass 2).
__global__ __launch_bounds__(256, 4) void scores_kernel(
    const float* __restrict__ x,
    const float* __restrict__ We,
    const float* __restrict__ Wg,
    float* __restrict__ scores)
{
    __shared__ float4 wlds[18 * SEGF4];   // 36,864 B

    const int tid   = threadIdx.x;
    const int seg   = blockIdx.x & 3;
    const int strip = blockIdx.x >> 2;

    const float4* __restrict__ x4  = reinterpret_cast<const float4*>(x);
    const float4* __restrict__ We4 = reinterpret_cast<const float4*>(We);
    const float4* __restrict__ Wg4 = reinterpret_cast<const float4*>(Wg);

    // Stage the 18 x 512-dim W segment into LDS (coalesced, conflict-free).
#pragma unroll
    for (int k = 0; k < 9; ++k) {
        const int idx = k * 256 + tid;        // 0..2303 float4
        const int e = idx >> 7;               // 0..17
        const int d = idx & 127;
        const float4* src = (e < 16) ? (We4 + (size_t)e * D4)
                                     : (Wg4 + (size_t)(e - 16) * D4);
        wlds[idx] = src[seg * SEGF4 + d];
    }
    __syncthreads();

    const int wave = tid >> 6;
    const int lane = tid & 63;
    const int grp  = lane >> 4;
    const int l16  = lane & 15;
    const int tokbase = strip * 64 + wave * 16 + grp * 4;

    const float4* __restrict__ xr0 = x4 + (size_t)(tokbase + 0) * D4 + seg * SEGF4;
    const float4* __restrict__ xr1 = x4 + (size_t)(tokbase + 1) * D4 + seg * SEGF4;
    const float4* __restrict__ xr2 = x4 + (size_t)(tokbase + 2) * D4 + seg * SEGF4;
    const float4* __restrict__ xr3 = x4 + (size_t)(tokbase + 3) * D4 + seg * SEGF4;

#pragma unroll
    for (int pass = 0; pass < 2; ++pass) {
        float acc0[9], acc1[9], acc2[9], acc3[9];
#pragma unroll
        for (int j = 0; j < 9; ++j) { acc0[j]=0.f; acc1[j]=0.f; acc2[j]=0.f; acc3[j]=0.f; }

#pragma unroll 2
        for (int it = 0; it < 8; ++it) {
            const int off = it * 16 + l16;
            // 4 global b128 (batched vmcnt) ...
            const float4 xv0 = xr0[off];
            const float4 xv1 = xr1[off];
            const float4 xv2 = xr2[off];
            const float4 xv3 = xr3[off];
            // ... + 9 LDS b128 (batched lgkmcnt, pipelined ~12 cyc apart)
            float4 w[9];
#pragma unroll
            for (int j = 0; j < 9; ++j)
                w[j] = wlds[(pass * 9 + j) * SEGF4 + off];
            // 144 FMAs on the batch
#pragma unroll
            for (int j = 0; j < 9; ++j) {
                acc0[j] += DOT4(w[j], xv0);
                acc1[j] += DOT4(w[j], xv1);
                acc2[j] += DOT4(w[j], xv2);
                acc3[j] += DOT4(w[j], xv3);
            }
        }

        // Reduce the 36 sums across each 16-lane group (pure VALU) and write.
#pragma unroll
        for (int j = 0; j < 9; ++j) {
            acc0[j] = row_reduce16(acc0[j]);
            acc1[j] = row_reduce16(acc1[j]);
            acc2[j] = row_reduce16(acc2[j]);
            acc3[j] = row_reduce16(acc3[j]);
        }
        if (l16 == 0) {
#pragma unroll
            for (int j = 0; j < 9; ++j) {
                float* p = scores + (size_t)(seg * 18 + pass * 9 + j) * NTOK + tokbase;
                p[0] = acc0[j];
                p[1] = acc1[j];
                p[2] = acc2[j];
                p[3] = acc3[j];
            }
        }
    }
}

// ---------------- Phase 2: combine segments + routing + aux ----------------
__global__ __launch_bounds__(256) void route_kernel(
    const float* __restrict__ scores,
    float* __restrict__ out,
    unsigned int* __restrict__ gcounts)
{
    __shared__ unsigned int lcnt[16];
    const int tid = threadIdx.x;
    if (tid < 16) lcnt[tid] = 0u;
    __syncthreads();

    const int tok = blockIdx.x * 256 + tid;

    float s[18];
#pragma unroll
    for (int e = 0; e < 18; ++e) {
        s[e] = scores[(size_t)(0 * 18 + e) * NTOK + tok]
             + scores[(size_t)(1 * 18 + e) * NTOK + tok]
             + scores[(size_t)(2 * 18 + e) * NTOK + tok]
             + scores[(size_t)(3 * 18 + e) * NTOK + tok];
    }

    const float g0 = 1.f / (1.f + expf(-s[16]));
    const float g1 = 1.f / (1.f + expf(-s[17]));

    // --- Group A: experts 0..7, top-1 of softmax ---
    int aidx = 0; float amax = s[0];
#pragma unroll
    for (int i = 1; i < 8; ++i)
        if (s[i] > amax) { amax = s[i]; aidx = i; }
    float asum = 0.f;
#pragma unroll
    for (int i = 0; i < 8; ++i) asum += expf(s[i] - amax);
    const float a_best = 1.f / asum;

    // --- Group B: experts 8..11, top-1, gated by g0 ---
    int bidx = 0; float bmax = s[8];
#pragma unroll
    for (int i = 1; i < 4; ++i)
        if (s[8 + i] > bmax) { bmax = s[8 + i]; bidx = i; }
    float bsum = 0.f;
#pragma unroll
    for (int i = 0; i < 4; ++i) bsum += expf(s[8 + i] - bmax);
    const float b_w = (g0 > 0.15f) ? ((1.f / bsum) * g0) : 0.f;

    // --- Group C: experts 12..15, top-2 of softmax, gated by g1 ---
    int c1 = 0; float cmax = s[12];
#pragma unroll
    for (int i = 1; i < 4; ++i)
        if (s[12 + i] > cmax) { cmax = s[12 + i]; c1 = i; }
    float csum = 0.f;
#pragma unroll
    for (int i = 0; i < 4; ++i) csum += expf(s[12 + i] - cmax);
    int c2 = -1; float c2v = -1e30f;
#pragma unroll
    for (int i = 0; i < 4; ++i)
        if (i != c1 && s[12 + i] > c2v) { c2v = s[12 + i]; c2 = i; }
    const float cg   = (g1 > 0.15f) ? g1 : 0.f;
    const float c_w1 = (1.f / csum) * cg;
    const float c_w2 = (expf(c2v - cmax) / csum) * cg;

    // --- normalize and write ---
    const float inv = 1.f / (a_best + b_w + c_w1 + c_w2 + 1e-8f);
    float2* ow = reinterpret_cast<float2*>(out + (size_t)tok * 6);
    ow[0] = make_float2(a_best * inv, b_w * inv);
    ow[1] = make_float2(c_w1 * inv, c_w2 * inv);
    ow[2] = make_float2(0.f, 0.f);
    float2* oi = reinterpret_cast<float2*>(out + NW6 + (size_t)tok * 6);
    oi[0] = make_float2((float)aidx, (float)(8 + bidx));
    oi[1] = make_float2((float)(12 + c1), (float)(12 + c2));
    oi[2] = make_float2(0.f, 0.f);

    atomicAdd(&lcnt[aidx], 1u);
    atomicAdd(&lcnt[8 + bidx], 1u);
    atomicAdd(&lcnt[12 + c1], 1u);
    atomicAdd(&lcnt[12 + c2], 1u);

    __syncthreads();
    if (tid < 16) {
        const unsigned int c = lcnt[tid];
        if (c) atomicAdd(&gcounts[tid], c);
    }
    __syncthreads();

    // Last-block ticket: aux loss. Reference bincount counts the 2 zero-pad
    // indices per token -> expert 0 gets +2*NTOK; total = 6*NTOK.
    if (tid == 0) {
        __threadfence();
        const unsigned int t = atomicAdd(&gcounts[16], 1u);
        if (t == gridDim.x - 1) {
            const float total = 6.0f * (float)NTOK;
            const float uni = 1.0f / 16.0f;
            float aux = 0.f;
            for (int e = 0; e < 16; ++e) {
                float c = (float)atomicAdd(&gcounts[e], 0u)
                          + (e == 0 ? 2.0f * (float)NTOK : 0.0f);
                aux += uni * (logf(uni) - logf(c / total));
            }
            out[2 * NW6] = aux * 0.01f;
        }
    }
}

extern "C" void kernel_launch(void* const* d_in, const int* in_sizes, int n_in,
                              void* d_out, int out_size, void* d_ws, size_t ws_size,
                              hipStream_t stream)
{
    const float* x  = (const float*)d_in[0];   // (4,4096,2048)
    const float* We = (const float*)d_in[1];   // (16,2048)
    const float* Wg = (const float*)d_in[2];   // (2,2048)
    float* out = (float*)d_out;

    float* scores = (float*)d_ws;                          // 4.72 MB
    unsigned int* counts = (unsigned int*)((char*)d_ws + SCORES_FLOATS * 4);

    hipMemsetAsync(counts, 0, 17 * sizeof(unsigned int), stream);

    // Phase 1: 64-token strips x 4 D-segments = 1024 blocks (4/CU).
    scores_kernel<<<dim3(1024), 256, 0, stream>>>(x, We, Wg, scores);
    // Phase 2 (stream-ordered after phase 1).
    route_kernel<<<dim3(NTOK / 256), 256, 0, stream>>>(scores, out, counts);
}

// Round 11
// 211.842 us; speedup vs baseline: 1.3268x; 1.0839x over previous
//
#include <hip/hip_runtime.h>
#include <math.h>
#include <stdint.h>

#define NTOK  16384
#define NW6   (NTOK * 6)
#define NSEG  4
#define SEGF4 128              // float4 per expert-row segment (512 dims)
#define D4    512              // float4 per full row
#define WF4   (18 * SEGF4)     // 2304 float4 of W per segment
#define XSF4  1024             // 64 tokens x 16 float4 per x buffer
#define NCH   8                // 64-dim chunks per 512-dim segment
#define SCORES_FLOATS (NSEG * 18 * NTOK)   // 4.72 MB

#define DOT4(a, b) ((a).x*(b).x + (a).y*(b).y + (a).z*(b).z + (a).w*(b).w)

// Async global->LDS DMA, 16 B per lane. LDS dest = wave-uniform base +
// lane*16 (contiguous); global src is per-lane. No destination VGPRs.
#define ASYNC_CP16(gsrc, ldst)                                              \
    __builtin_amdgcn_global_load_lds(                                       \
        (const __attribute__((address_space(1))) void*)(gsrc),              \
        (__attribute__((address_space(3))) void*)(ldst), 16, 0, 0)

// DPP row_shl sum-tree: lane i adds lane i+N (out-of-range -> 0). After 4
// steps lane 0 of each 16-lane row holds the full row sum. (Verified R6+.)
template <int CTRL>
__device__ __forceinline__ float dpp_add(float v) {
    int moved = __builtin_amdgcn_update_dpp(0, __float_as_int(v),
                                            CTRL, 0xF, 0xF, true);
    return v + __int_as_float(moved);
}
__device__ __forceinline__ float row_reduce16(float v) {
    v = dpp_add<0x108>(v);   // row_shl:8
    v = dpp_add<0x104>(v);   // row_shl:4
    v = dpp_add<0x102>(v);   // row_shl:2
    v = dpp_add<0x101>(v);   // row_shl:1
    return v;
}

// ---------------- Phase 1: partial scores per D-segment ----------------
// m97-style structure: ALL global->LDS traffic via async DMA (zero VGPR
// round-trips -- the R6/R8/R10 failure mode is structurally removed).
// Block: 4 waves, 64 tokens, one 512-dim segment. LDS: W segment 36 KB +
// x double buffer 2 x 16 KB (64 tok x 64 dims). Compute reads only LDS.
__global__ __launch_bounds__(256, 2) void scores_kernel(
    const float* __restrict__ x,
    const float* __restrict__ We,
    const float* __restrict__ Wg,
    float* __restrict__ scores)
{
    __shared__ float4 smem[WF4 + 2 * XSF4];   // 36,864 + 32,768 B

    const int tid   = threadIdx.x;
    const int seg   = blockIdx.x & 3;
    const int strip = blockIdx.x >> 2;

    const float4* __restrict__ x4  = reinterpret_cast<const float4*>(x);
    const float4* __restrict__ We4 = reinterpret_cast<const float4*>(We);
    const float4* __restrict__ Wg4 = reinterpret_cast<const float4*>(Wg);

    const int wave = tid >> 6;
    const int lane = tid & 63;
    const int grp  = lane >> 4;
    const int l16  = lane & 15;

    // ---- prologue: DMA the W segment (9 instr/wave) ----
#pragma unroll
    for (int k = 0; k < 9; ++k) {
        const int idx = wave * 576 + k * 64 + lane;    // 0..2303
        const int e = idx >> 7;                        // 0..17
        const int d = idx & 127;
        const float4* gsrc = ((e < 16) ? (We4 + (size_t)e * D4)
                                       : (Wg4 + (size_t)(e - 16) * D4))
                             + seg * SEGF4 + d;
        ASYNC_CP16(gsrc, smem + wave * 576 + k * 64);
    }

    // ---- prologue: DMA x chunk 0 into buffer 0 (4 instr/wave) ----
    const int rowbase = strip * 64 + wave * 16;        // this wave's 16 tokens
#pragma unroll
    for (int i = 0; i < 4; ++i) {
        const float4* gsrc = x4 + (size_t)(rowbase + i * 4 + (lane >> 4)) * D4
                             + seg * SEGF4 + (lane & 15);
        ASYNC_CP16(gsrc, smem + WF4 + (wave * 16 + i * 4) * 16);
    }
    __syncthreads();   // vmcnt(0) drain: W + chunk 0 resident

    float acc0[18], acc1[18], acc2[18], acc3[18];
#pragma unroll
    for (int e = 0; e < 18; ++e) { acc0[e]=0.f; acc1[e]=0.f; acc2[e]=0.f; acc3[e]=0.f; }

    for (int ch = 0; ch < NCH; ++ch) {
        const int cur = ch & 1;
        const int nxt = cur ^ 1;

        // Issue next chunk's DMA first -- in flight across the whole compute.
        if (ch + 1 < NCH) {
#pragma unroll
            for (int i = 0; i < 4; ++i) {
                const float4* gsrc = x4
                    + (size_t)(rowbase + i * 4 + (lane >> 4)) * D4
                    + seg * SEGF4 + (ch + 1) * 16 + (lane & 15);
                ASYNC_CP16(gsrc, smem + WF4 + nxt * XSF4 + (wave * 16 + i * 4) * 16);
            }
        }

        // Compute on current buffer (LDS only; fine-grained lgkm pipelining).
        const float4* xcur = smem + WF4 + cur * XSF4 + (wave * 16 + grp * 4) * 16 + l16;
        const float4 xv0 = xcur[0];
        const float4 xv1 = xcur[16];
        const float4 xv2 = xcur[32];
        const float4 xv3 = xcur[48];

#pragma unroll
        for (int e = 0; e < 18; ++e) {
            const float4 w = smem[e * SEGF4 + ch * 16 + l16];  // broadcast, 2-way
            acc0[e] += DOT4(w, xv0);
            acc1[e] += DOT4(w, xv1);
            acc2[e] += DOT4(w, xv2);
            acc3[e] += DOT4(w, xv3);
        }

        __syncthreads();   // drains nxt-chunk DMA; protects buffer swap
    }

    // ---- reduce 72 sums across each 16-lane group (pure VALU) ----
#pragma unroll
    for (int e = 0; e < 18; ++e) {
        acc0[e] = row_reduce16(acc0[e]);
        acc1[e] = row_reduce16(acc1[e]);
        acc2[e] = row_reduce16(acc2[e]);
        acc3[e] = row_reduce16(acc3[e]);
    }

    if (l16 == 0) {
        const int tokbase = strip * 64 + wave * 16 + grp * 4;
#pragma unroll
        for (int e = 0; e < 18; ++e) {
            float* p = scores + (size_t)(seg * 18 + e) * NTOK + tokbase;
            p[0] = acc0[e];
            p[1] = acc1[e];
            p[2] = acc2[e];
            p[3] = acc3[e];
        }
    }
}

// ---------------- Phase 2: combine segments + routing + aux ----------------
__global__ __launch_bounds__(256) void route_kernel(
    const float* __restrict__ scores,
    float* __restrict__ out,
    unsigned int* __restrict__ gcounts)
{
    __shared__ unsigned int lcnt[16];
    const int tid = threadIdx.x;
    if (tid < 16) lcnt[tid] = 0u;
    __syncthreads();

    const int tok = blockIdx.x * 256 + tid;

    float s[18];
#pragma unroll
    for (int e = 0; e < 18; ++e) {
        s[e] = scores[(size_t)(0 * 18 + e) * NTOK + tok]
             + scores[(size_t)(1 * 18 + e) * NTOK + tok]
             + scores[(size_t)(2 * 18 + e) * NTOK + tok]
             + scores[(size_t)(3 * 18 + e) * NTOK + tok];
    }

    const float g0 = 1.f / (1.f + expf(-s[16]));
    const float g1 = 1.f / (1.f + expf(-s[17]));

    // --- Group A: experts 0..7, top-1 of softmax ---
    int aidx = 0; float amax = s[0];
#pragma unroll
    for (int i = 1; i < 8; ++i)
        if (s[i] > amax) { amax = s[i]; aidx = i; }
    float asum = 0.f;
#pragma unroll
    for (int i = 0; i < 8; ++i) asum += expf(s[i] - amax);
    const float a_best = 1.f / asum;

    // --- Group B: experts 8..11, top-1, gated by g0 ---
    int bidx = 0; float bmax = s[8];
#pragma unroll
    for (int i = 1; i < 4; ++i)
        if (s[8 + i] > bmax) { bmax = s[8 + i]; bidx = i; }
    float bsum = 0.f;
#pragma unroll
    for (int i = 0; i < 4; ++i) bsum += expf(s[8 + i] - bmax);
    const float b_w = (g0 > 0.15f) ? ((1.f / bsum) * g0) : 0.f;

    // --- Group C: experts 12..15, top-2 of softmax, gated by g1 ---
    int c1 = 0; float cmax = s[12];
#pragma unroll
    for (int i = 1; i < 4; ++i)
        if (s[12 + i] > cmax) { cmax = s[12 + i]; c1 = i; }
    float csum = 0.f;
#pragma unroll
    for (int i = 0; i < 4; ++i) csum += expf(s[12 + i] - cmax);
    int c2 = -1; float c2v = -1e30f;
#pragma unroll
    for (int i = 0; i < 4; ++i)
        if (i != c1 && s[12 + i] > c2v) { c2v = s[12 + i]; c2 = i; }
    const float cg   = (g1 > 0.15f) ? g1 : 0.f;
    const float c_w1 = (1.f / csum) * cg;
    const float c_w2 = (expf(c2v - cmax) / csum) * cg;

    // --- normalize and write ---
    const float inv = 1.f / (a_best + b_w + c_w1 + c_w2 + 1e-8f);
    float2* ow = reinterpret_cast<float2*>(out + (size_t)tok * 6);
    ow[0] = make_float2(a_best * inv, b_w * inv);
    ow[1] = make_float2(c_w1 * inv, c_w2 * inv);
    ow[2] = make_float2(0.f, 0.f);
    float2* oi = reinterpret_cast<float2*>(out + NW6 + (size_t)tok * 6);
    oi[0] = make_float2((float)aidx, (float)(8 + bidx));
    oi[1] = make_float2((float)(12 + c1), (float)(12 + c2));
    oi[2] = make_float2(0.f, 0.f);

    atomicAdd(&lcnt[aidx], 1u);
    atomicAdd(&lcnt[8 + bidx], 1u);
    atomicAdd(&lcnt[12 + c1], 1u);
    atomicAdd(&lcnt[12 + c2], 1u);

    __syncthreads();
    if (tid < 16) {
        const unsigned int c = lcnt[tid];
        if (c) atomicAdd(&gcounts[tid], c);
    }
    __syncthreads();

    // Last-block ticket: aux loss. Reference bincount counts the 2 zero-pad
    // indices per token -> expert 0 gets +2*NTOK; total = 6*NTOK.
    if (tid == 0) {
        __threadfence();
        const unsigned int t = atomicAdd(&gcounts[16], 1u);
        if (t == gridDim.x - 1) {
            const float total = 6.0f * (float)NTOK;
            const float uni = 1.0f / 16.0f;
            float aux = 0.f;
            for (int e = 0; e < 16; ++e) {
                float c = (float)atomicAdd(&gcounts[e], 0u)
                          + (e == 0 ? 2.0f * (float)NTOK : 0.0f);
                aux += uni * (logf(uni) - logf(c / total));
            }
            out[2 * NW6] = aux * 0.01f;
        }
    }
}

extern "C" void kernel_launch(void* const* d_in, const int* in_sizes, int n_in,
                              void* d_out, int out_size, void* d_ws, size_t ws_size,
                              hipStream_t stream)
{
    const float* x  = (const float*)d_in[0];   // (4,4096,2048)
    const float* We = (const float*)d_in[1];   // (16,2048)
    const float* Wg = (const float*)d_in[2];   // (2,2048)
    float* out = (float*)d_out;

    float* scores = (float*)d_ws;                          // 4.72 MB
    unsigned int* counts = (unsigned int*)((char*)d_ws + SCORES_FLOATS * 4);

    hipMemsetAsync(counts, 0, 17 * sizeof(unsigned int), stream);

    // Phase 1: 256 token-strips x 4 D-segments = 1024 blocks.
    scores_kernel<<<dim3(1024), 256, 0, stream>>>(x, We, Wg, scores);
    // Phase 2 (stream-ordered after phase 1).
    route_kernel<<<dim3(NTOK / 256), 256, 0, stream>>>(scores, out, counts);
}